// Round 1
// baseline (214.825 us; speedup 1.0000x reference)
//
#include <hip/hip_runtime.h>
#include <stdint.h>

typedef __attribute__((ext_vector_type(8))) short short8;
typedef __attribute__((ext_vector_type(4))) float f32x4;

constexpr int Hc = 128, Wc = 128, HWc = Hc * Wc;
constexpr int Cin = 128, Cout = 128;
constexpr int OffC = 18, OffIn = 64;

__device__ __forceinline__ float bf2f(unsigned short u) {
    return __builtin_bit_cast(float, (unsigned)u << 16);
}
__device__ __forceinline__ unsigned short f2bf(float f) {
    unsigned u = __builtin_bit_cast(unsigned, f);
    return (unsigned short)((u + 0x7FFFu + ((u >> 16) & 1u)) >> 16);
}

// ---- 1x1 offset conv: off [B,64,HW] x w_off [18,64] + b_off -> offset [B,18,HW]
__global__ void k_offconv(const float* __restrict__ off, const float* __restrict__ w_off,
                          const float* __restrict__ b_off, float* __restrict__ offset) {
    __shared__ float wsm[OffC * OffIn];
    __shared__ float bsm[OffC];
    int tid = threadIdx.x;
    for (int i = tid; i < OffC * OffIn; i += 256) wsm[i] = w_off[i];
    if (tid < OffC) bsm[tid] = b_off[tid];
    __syncthreads();
    int g = (blockIdx.x * 256 + tid) * 4;       // 4 pixels per thread
    int b = g >> 14, hw = g & (HWc - 1);
    const float* offb = off + b * OffIn * HWc + hw;
    float acc[OffC][4];
#pragma unroll
    for (int o = 0; o < OffC; ++o) {
        float bv = bsm[o];
        acc[o][0] = bv; acc[o][1] = bv; acc[o][2] = bv; acc[o][3] = bv;
    }
    for (int c = 0; c < OffIn; ++c) {
        float4 v = *(const float4*)(offb + (c << 14));
#pragma unroll
        for (int o = 0; o < OffC; ++o) {
            float wv = wsm[o * OffIn + c];
            acc[o][0] += wv * v.x; acc[o][1] += wv * v.y;
            acc[o][2] += wv * v.z; acc[o][3] += wv * v.w;
        }
    }
    float* outb = offset + b * OffC * HWc + hw;
#pragma unroll
    for (int o = 0; o < OffC; ++o) {
        float4 v; v.x = acc[o][0]; v.y = acc[o][1]; v.z = acc[o][2]; v.w = acc[o][3];
        *(float4*)(outb + (o << 14)) = v;
    }
}

// ---- x [B,C,H,W] fp32 -> x_t [B,H,W,C] bf16 (channels-last for coalesced gather)
__global__ void k_xpose(const float* __restrict__ x, unsigned short* __restrict__ xt) {
    __shared__ float tile[128][65];
    int blk = blockIdx.x;
    int b = blk >> 8;                  // 256 blocks per batch (16384/64 pixels)
    int hw0 = (blk & 255) << 6;        // 64 pixels per block
    const float* xb = x + b * Cin * HWc;
    int tid = threadIdx.x;
#pragma unroll
    for (int k = 0; k < 32; ++k) {
        int e = tid + k * 256;
        int c = e >> 6, p = e & 63;
        tile[c][p] = xb[(c << 14) + hw0 + p];
    }
    __syncthreads();
    unsigned short* xtb = xt + ((b << 14) + hw0) * Cin;
#pragma unroll
    for (int k = 0; k < 32; ++k) {
        int e = tid + k * 256;
        int p = e >> 7, c = e & 127;
        xtb[e] = f2bf(tile[c][p]);
    }
}

// ---- w_def [O,C,3,3] fp32 -> Wt [kk][O][C] bf16 (c contiguous for A-fragments)
__global__ void k_wprep(const float* __restrict__ wd, unsigned short* __restrict__ wt) {
    int i = blockIdx.x * 256 + threadIdx.x;   // grid exactly 9*128*128/256 = 576
    int kk = i >> 14, o = (i >> 7) & 127, c = i & 127;
    wt[i] = f2bf(wd[((o << 7) + c) * 9 + kk]);
}

// ---- main: per block 64 pixels x 128 outputs; per tap gather->LDS then MFMA
__global__ __launch_bounds__(256)
void k_deform(const unsigned short* __restrict__ xt, const float* __restrict__ offset,
              const unsigned short* __restrict__ wt, float* __restrict__ out) {
    __shared__ float offs[OffC][64];
    __shared__ float wgt[9][4][64];
    __shared__ int cbase[9][4][64];
    __shared__ __align__(16) unsigned short vt[64 * 128];   // [p][c] bf16, XOR-swizzled

    int tid = threadIdx.x;
    int blk = blockIdx.x;
    int b = blk >> 8;
    int hw0 = (blk & 255) << 6;

    // stage the 18 offset channels for our 64 pixels
    const float* offg = offset + b * OffC * HWc + hw0;
    for (int i = tid; i < OffC * 64; i += 256)
        offs[i >> 6][i & 63] = offg[((i >> 6) << 14) + (i & 63)];
    __syncthreads();

    // precompute bilinear corner bases + masked weights for all 9 taps x 64 pixels
    for (int t = tid; t < 576; t += 256) {
        int tap = t >> 6, p = t & 63;
        int hw = hw0 + p, h = hw >> 7, w = hw & 127;
        float dy = offs[2 * tap][p], dx = offs[2 * tap + 1][p];
        float ys = (float)(h - 1 + tap / 3) + dy;
        float xs = (float)(w - 1 + tap % 3) + dx;
        float y0f = floorf(ys), x0f = floorf(xs);
        float ly = ys - y0f, lx = xs - x0f;
        int y0 = (int)y0f, x0 = (int)x0f;
#pragma unroll
        for (int cr = 0; cr < 4; ++cr) {
            int yi = y0 + (cr >> 1), xi = x0 + (cr & 1);
            bool valid = (yi >= 0) && (yi < Hc) && (xi >= 0) && (xi < Wc);
            float wy = (cr >> 1) ? ly : 1.0f - ly;
            float wx = (cr & 1) ? lx : 1.0f - lx;
            int yc = yi < 0 ? 0 : (yi > Hc - 1 ? Hc - 1 : yi);
            int xc = xi < 0 ? 0 : (xi > Wc - 1 ? Wc - 1 : xi);
            wgt[tap][cr][p] = valid ? wy * wx : 0.0f;
            cbase[tap][cr][p] = ((yc << 7) + xc) << 7;    // element offset within batch
        }
    }

    f32x4 acc[2][4];
#pragma unroll
    for (int i = 0; i < 2; ++i)
#pragma unroll
        for (int j = 0; j < 4; ++j)
            acc[i][j] = (f32x4){0.f, 0.f, 0.f, 0.f};

    int lane = tid & 63, wave = tid >> 6;
    const unsigned short* xb = xt + (b << 14) * Cin;
    char* vtb = (char*)vt;
    int c4 = (tid & 31) << 2;    // 4 channels per thread in gather

    for (int tap = 0; tap < 9; ++tap) {
        __syncthreads();   // vt free (prev MFMA done) / params visible (tap 0)
        // gather: 8 passes x (8 pixels x 128 channels), coalesced 8B loads from x_t
        for (int pass = 0; pass < 8; ++pass) {
            int p = (tid >> 5) + (pass << 3);
            float v0 = 0.f, v1 = 0.f, v2 = 0.f, v3 = 0.f;
#pragma unroll
            for (int cr = 0; cr < 4; ++cr) {
                float wc = wgt[tap][cr][p];
                const unsigned short* src = xb + cbase[tap][cr][p] + c4;
                ushort4 raw = *(const ushort4*)src;
                v0 += wc * bf2f(raw.x);
                v1 += wc * bf2f(raw.y);
                v2 += wc * bf2f(raw.z);
                v3 += wc * bf2f(raw.w);
            }
            ushort4 pk;
            pk.x = f2bf(v0); pk.y = f2bf(v1); pk.z = f2bf(v2); pk.w = f2bf(v3);
            int byteoff = ((p << 8) + (c4 << 1)) ^ ((p & 7) << 4);
            *(ushort4*)(vtb + byteoff) = pk;
        }
        __syncthreads();
        // MFMA: D[o 16][p 16] tiles; wave handles o in [wave*32, wave*32+32)
        const unsigned short* wtap = wt + (tap << 14);
        int orow = wave << 5;
#pragma unroll
        for (int kb = 0; kb < 4; ++kb) {
            int kc = (kb << 5) + ((lane >> 4) << 3);
            short8 a0 = *(const short8*)(wtap + (orow + (lane & 15)) * 128 + kc);
            short8 a1 = *(const short8*)(wtap + (orow + 16 + (lane & 15)) * 128 + kc);
#pragma unroll
            for (int pb = 0; pb < 4; ++pb) {
                int p = (pb << 4) + (lane & 15);
                int byteoff = ((p << 8) + (kc << 1)) ^ ((p & 7) << 4);
                short8 bfrag = *(const short8*)(vtb + byteoff);
                acc[0][pb] = __builtin_amdgcn_mfma_f32_16x16x32_bf16(a0, bfrag, acc[0][pb], 0, 0, 0);
                acc[1][pb] = __builtin_amdgcn_mfma_f32_16x16x32_bf16(a1, bfrag, acc[1][pb], 0, 0, 0);
            }
        }
    }

    // epilogue: ReLU + fp32 store. D mapping: col(p)=lane&15, row(o)=(lane>>4)*4+j
    float* outb = out + (b * Cout) * HWc + hw0;
    int orow2 = wave << 5;
#pragma unroll
    for (int ob = 0; ob < 2; ++ob)
#pragma unroll
        for (int pb = 0; pb < 4; ++pb)
#pragma unroll
            for (int j = 0; j < 4; ++j) {
                int o = orow2 + (ob << 4) + ((lane >> 4) << 2) + j;
                int p = (pb << 4) + (lane & 15);
                float v = acc[ob][pb][j];
                outb[o * HWc + p] = v > 0.f ? v : 0.f;
            }
}

extern "C" void kernel_launch(void* const* d_in, const int* in_sizes, int n_in,
                              void* d_out, int out_size, void* d_ws, size_t ws_size,
                              hipStream_t stream) {
    const float* x     = (const float*)d_in[0];
    const float* off   = (const float*)d_in[1];
    const float* w_off = (const float*)d_in[2];
    const float* b_off = (const float*)d_in[3];
    const float* w_def = (const float*)d_in[4];
    float* out = (float*)d_out;

    char* ws = (char*)d_ws;
    float* offset      = (float*)ws;                                  // 4*18*16384*4   = 4,718,592 B
    unsigned short* xt = (unsigned short*)(ws + 4718592);             // 4*16384*128*2  = 16,777,216 B
    unsigned short* wt = (unsigned short*)(ws + 4718592 + 16777216);  // 9*128*128*2    = 294,912 B

    hipLaunchKernelGGL(k_offconv, dim3(64),   dim3(256), 0, stream, off, w_off, b_off, offset);
    hipLaunchKernelGGL(k_xpose,   dim3(1024), dim3(256), 0, stream, x, xt);
    hipLaunchKernelGGL(k_wprep,   dim3(576),  dim3(256), 0, stream, w_def, wt);
    hipLaunchKernelGGL(k_deform,  dim3(1024), dim3(256), 0, stream, xt, offset, wt, out);
}

// Round 2
// 206.685 us; speedup vs baseline: 1.0394x; 1.0394x over previous
//
#include <hip/hip_runtime.h>
#include <stdint.h>

typedef __attribute__((ext_vector_type(8))) short short8;
typedef __attribute__((ext_vector_type(4))) float f32x4;

constexpr int Hc = 128, Wc = 128, HWc = Hc * Wc;
constexpr int Cin = 128, Cout = 128;
constexpr int OffC = 18, OffIn = 64;

__device__ __forceinline__ float bf2f(unsigned short u) {
    return __builtin_bit_cast(float, (unsigned)u << 16);
}
__device__ __forceinline__ unsigned short f2bf(float f) {
    unsigned u = __builtin_bit_cast(unsigned, f);
    return (unsigned short)((u + 0x7FFFu + ((u >> 16) & 1u)) >> 16);
}

// ---- 1x1 offset conv: off [B,64,HW] x w_off [18,64] + b_off -> offset [B,18,HW]
// 256 blocks (full chip), 1 pixel/thread.
__global__ void k_offconv(const float* __restrict__ off, const float* __restrict__ w_off,
                          const float* __restrict__ b_off, float* __restrict__ offset) {
    __shared__ float wsm[OffC * OffIn];
    __shared__ float bsm[OffC];
    int tid = threadIdx.x;
    for (int i = tid; i < OffC * OffIn; i += 256) wsm[i] = w_off[i];
    if (tid < OffC) bsm[tid] = b_off[tid];
    __syncthreads();
    int g = blockIdx.x * 256 + tid;            // one pixel per thread
    int b = g >> 14, hw = g & (HWc - 1);
    const float* offb = off + b * OffIn * HWc + hw;
    float acc[OffC];
#pragma unroll
    for (int o = 0; o < OffC; ++o) acc[o] = bsm[o];
    for (int c = 0; c < OffIn; ++c) {
        float v = offb[c << 14];
#pragma unroll
        for (int o = 0; o < OffC; ++o) acc[o] += wsm[o * OffIn + c] * v;
    }
    float* outb = offset + b * OffC * HWc + hw;
#pragma unroll
    for (int o = 0; o < OffC; ++o) outb[o << 14] = acc[o];
}

// ---- x [B,C,H,W] fp32 -> x_t [B,H,W,C] bf16 (channels-last for coalesced gather)
__global__ void k_xpose(const float* __restrict__ x, unsigned short* __restrict__ xt) {
    __shared__ float tile[128][65];
    int blk = blockIdx.x;
    int b = blk >> 8;                  // 256 blocks per batch (16384/64 pixels)
    int hw0 = (blk & 255) << 6;        // 64 pixels per block
    const float* xb = x + b * Cin * HWc;
    int tid = threadIdx.x;
#pragma unroll
    for (int k = 0; k < 32; ++k) {
        int e = tid + k * 256;
        int c = e >> 6, p = e & 63;
        tile[c][p] = xb[(c << 14) + hw0 + p];
    }
    __syncthreads();
    unsigned short* xtb = xt + ((b << 14) + hw0) * Cin;
#pragma unroll
    for (int k = 0; k < 16; ++k) {
        int e = (tid + k * 256) * 2;   // even, covers 0..8190
        int p = e >> 7, c = e & 127;   // c even
        unsigned lo = f2bf(tile[c][p]);
        unsigned hi = f2bf(tile[c + 1][p]);
        *(unsigned*)(xtb + e) = lo | (hi << 16);
    }
}

// ---- w_def [O,C,3,3] fp32 -> Wt [kk][O][C] bf16 (c contiguous for A-fragments)
__global__ void k_wprep(const float* __restrict__ wd, unsigned short* __restrict__ wt) {
    int i = blockIdx.x * 256 + threadIdx.x;   // grid exactly 9*128*128/256 = 576
    int kk = i >> 14, o = (i >> 7) & 127, c = i & 127;
    wt[i] = f2bf(wd[((o << 7) + c) * 9 + kk]);
}

// ---- main: 512 blocks x 512 threads. 128 px x 128 out per block.
// Double-buffered v-tile in LDS; gather loads for tap t+1 issued before MFMA(t).
__global__ __launch_bounds__(512, 4)
void k_deform(const unsigned short* __restrict__ xt, const float* __restrict__ offset,
              const unsigned short* __restrict__ wt, float* __restrict__ out) {
    __shared__ float offs[OffC][128];
    __shared__ __align__(16) unsigned short vt[2][128 * 128];   // [buf][px][c], XOR-swizzled

    int tid = threadIdx.x;
    int bid = blockIdx.x;
    int swz = (bid & 7) * 64 + (bid >> 3);     // XCD-bijective (512 % 8 == 0)
    int b = swz >> 7;
    int hw0 = (swz & 127) << 7;                // 128 pixels

    // stage 18 offset channels for our 128 pixels
    const float* offg = offset + b * OffC * HWc + hw0;
    for (int i = tid; i < OffC * 128; i += 512)
        offs[i >> 7][i & 127] = offg[((i >> 7) << 14) + (i & 127)];
    __syncthreads();

    int px = tid >> 2;                 // 0..127: this thread's pixel (all taps)
    int cq = tid & 3;                  // channel quarter
    int c0 = cq * 8;                   // + i*32 -> 8 channels per load
    int h = (hw0 + px) >> 7, w = (hw0 + px) & 127;
    const unsigned short* xb = xt + (size_t)(b << 14) * Cin;
    char* vtb = (char*)vt;

    float cw[4]; int cb[4];
    auto calc_params = [&](int tap) {
        float dy = offs[2 * tap][px], dx = offs[2 * tap + 1][px];
        float ys = (float)(h - 1 + tap / 3) + dy;
        float xs = (float)(w - 1 + tap % 3) + dx;
        float y0f = floorf(ys), x0f = floorf(xs);
        float ly = ys - y0f, lx = xs - x0f;
        int y0 = (int)y0f, x0 = (int)x0f;
#pragma unroll
        for (int cr = 0; cr < 4; ++cr) {
            int yi = y0 + (cr >> 1), xi = x0 + (cr & 1);
            bool valid = (yi >= 0) && (yi < Hc) && (xi >= 0) && (xi < Wc);
            float wy = (cr >> 1) ? ly : 1.0f - ly;
            float wx = (cr & 1) ? lx : 1.0f - lx;
            int yc = yi < 0 ? 0 : (yi > Hc - 1 ? Hc - 1 : yi);
            int xc = xi < 0 ? 0 : (xi > Wc - 1 ? Wc - 1 : xi);
            cw[cr] = valid ? wy * wx : 0.0f;
            cb[cr] = ((yc << 7) + xc) << 7;
        }
    };
    auto issue = [&](short8* r, int i) {
#pragma unroll
        for (int cr = 0; cr < 4; ++cr)
            r[cr] = *(const short8*)(xb + cb[cr] + c0 + i * 32);
    };
    auto consume = [&](short8* r, int i, int buf) {
        float v[8];
#pragma unroll
        for (int k = 0; k < 8; ++k) {
            v[k] = cw[0] * bf2f((unsigned short)r[0][k])
                 + cw[1] * bf2f((unsigned short)r[1][k])
                 + cw[2] * bf2f((unsigned short)r[2][k])
                 + cw[3] * bf2f((unsigned short)r[3][k]);
        }
        short8 pk;
#pragma unroll
        for (int k = 0; k < 8; ++k) pk[k] = (short)f2bf(v[k]);
        int byteoff = ((px << 8) + ((c0 + i * 32) << 1)) ^ ((px & 7) << 4);
        *(short8*)(vtb + buf * 32768 + byteoff) = pk;
    };

    int lane = tid & 63, wave = tid >> 6;
    int obase = (wave >> 2) << 6;      // 0 / 64
    int pbase = (wave & 3) << 5;       // 0/32/64/96

    f32x4 acc[4][2];
#pragma unroll
    for (int i = 0; i < 4; ++i)
#pragma unroll
        for (int j = 0; j < 2; ++j)
            acc[i][j] = (f32x4){0.f, 0.f, 0.f, 0.f};

    auto mfma_half = [&](int buf, int tap, int kb0) {
        const unsigned short* wtap = wt + (tap << 14);
#pragma unroll
        for (int kb = kb0; kb < kb0 + 2; ++kb) {
            int kc = (kb << 5) + ((lane >> 4) << 3);
            int p0 = pbase + (lane & 15);
            int p1 = p0 + 16;
            short8 b0 = *(const short8*)(vtb + buf * 32768 + ((((p0 << 8) + (kc << 1)) ^ ((p0 & 7) << 4))));
            short8 b1 = *(const short8*)(vtb + buf * 32768 + ((((p1 << 8) + (kc << 1)) ^ ((p1 & 7) << 4))));
            short8 aa[4];
#pragma unroll
            for (int ot = 0; ot < 4; ++ot)
                aa[ot] = *(const short8*)(wtap + (obase + (ot << 4) + (lane & 15)) * 128 + kc);
#pragma unroll
            for (int ot = 0; ot < 4; ++ot) {
                acc[ot][0] = __builtin_amdgcn_mfma_f32_16x16x32_bf16(aa[ot], b0, acc[ot][0], 0, 0, 0);
                acc[ot][1] = __builtin_amdgcn_mfma_f32_16x16x32_bf16(aa[ot], b1, acc[ot][1], 0, 0, 0);
            }
        }
    };

    short8 r0[4], r1[4];

    // prologue: gather tap 0 into vt[0]
    calc_params(0);
    issue(r0, 0); issue(r1, 1);
    consume(r0, 0, 0); issue(r0, 2);
    consume(r1, 1, 0); issue(r1, 3);
    consume(r0, 2, 0); consume(r1, 3, 0);
    __syncthreads();

    for (int t = 0; t < 9; ++t) {
        int cur = t & 1;
        if (t < 8) {
            calc_params(t + 1);
            issue(r0, 0); issue(r1, 1);       // in flight across MFMA
        }
        mfma_half(cur, t, 0);
        if (t < 8) {
            consume(r0, 0, cur ^ 1); issue(r0, 2);
            consume(r1, 1, cur ^ 1); issue(r1, 3);
        }
        mfma_half(cur, t, 2);
        if (t < 8) {
            consume(r0, 2, cur ^ 1); consume(r1, 3, cur ^ 1);
        }
        __syncthreads();
    }

    // epilogue: ReLU + fp32 store. D mapping: col(p)=lane&15, row(o)=(lane>>4)*4+j
    float* outb = out + (size_t)(b * Cout) * HWc + hw0;
#pragma unroll
    for (int ot = 0; ot < 4; ++ot)
#pragma unroll
        for (int pb = 0; pb < 2; ++pb)
#pragma unroll
            for (int j = 0; j < 4; ++j) {
                int o = obase + (ot << 4) + ((lane >> 4) << 2) + j;
                int p = pbase + (pb << 4) + (lane & 15);
                float v = acc[ot][pb][j];
                outb[(o << 14) + p] = v > 0.f ? v : 0.f;
            }
}

extern "C" void kernel_launch(void* const* d_in, const int* in_sizes, int n_in,
                              void* d_out, int out_size, void* d_ws, size_t ws_size,
                              hipStream_t stream) {
    const float* x     = (const float*)d_in[0];
    const float* off   = (const float*)d_in[1];
    const float* w_off = (const float*)d_in[2];
    const float* b_off = (const float*)d_in[3];
    const float* w_def = (const float*)d_in[4];
    float* out = (float*)d_out;

    char* ws = (char*)d_ws;
    float* offset      = (float*)ws;                                  // 4,718,592 B
    unsigned short* xt = (unsigned short*)(ws + 4718592);             // 16,777,216 B
    unsigned short* wt = (unsigned short*)(ws + 4718592 + 16777216);  // 294,912 B

    hipLaunchKernelGGL(k_offconv, dim3(256),  dim3(256), 0, stream, off, w_off, b_off, offset);
    hipLaunchKernelGGL(k_xpose,   dim3(1024), dim3(256), 0, stream, x, xt);
    hipLaunchKernelGGL(k_wprep,   dim3(576),  dim3(256), 0, stream, w_def, wt);
    hipLaunchKernelGGL(k_deform,  dim3(512),  dim3(512), 0, stream, xt, offset, wt, out);
}